// Round 3
// baseline (185.861 us; speedup 1.0000x reference)
//
#include <hip/hip_runtime.h>

#define HD 32
#define QCH 8          // channels per thread (quarter of head_dim)
#define NQ 4           // channel quarters
#define NHEADS 12
#define HH 56
#define WW 56
#define NN (HH * WW)
#define BB 8
#define CC (HD * NHEADS)
#define PAIRS_PER_BLK 64   // pixel-pairs per block (x-dim); 128 pixels
#define NPAIRS (NN / 2)    // 1568
#define SCALE 0.17677669529663689f

// block (64,4)=256 threads. threadIdx.x -> pixel pair (2 consecutive n, same
// row since 56 is even), threadIdx.y -> 8-channel quarter. All k/v/q loads are
// float2 (512 B per wave-instruction). Aligned pairs + even dilation offsets
// mean both pixels of a tap share validity -> branch-free masked float2 path.
__global__ __launch_bounds__(256) void dilate_attn_kernel(
    const float* __restrict__ q,
    const float* __restrict__ k,
    const float* __restrict__ v,
    float* __restrict__ out)
{
    const int xi = threadIdx.x;           // 0..63 : pair within block
    const int qtr = threadIdx.y;          // 0..3  : channel quarter
    const int pair = blockIdx.x * PAIRS_PER_BLK + xi;
    const bool active = (pair < NPAIRS);
    const int n0 = 2 * pair;              // first pixel of pair
    const int y = n0 / WW;
    const int x0 = n0 - y * WW;           // even

    const int bh = blockIdx.y;
    const int b = bh / NHEADS;
    const int head = bh - b * NHEADS;

    const size_t base = ((size_t)b * CC + (size_t)head * HD + (size_t)qtr * QCH) * NN;

    // LDS: [quarter][tap][pair] float2 -> 8 B/lane contiguous, conflict-free
    __shared__ float2 part[NQ][9][PAIRS_PER_BLK];   // 18432 B

    // q fragment: 8 float2 loads, coalesced across lanes
    float2 qv[QCH];
#pragma unroll
    for (int d = 0; d < QCH; ++d) qv[d] = make_float2(0.f, 0.f);
    if (active) {
        const float* qb = q + base + n0;
#pragma unroll
        for (int d = 0; d < QCH; ++d)
            qv[d] = *reinterpret_cast<const float2*>(qb + (size_t)d * NN);
    }

    // partial QK logits over 9 taps (zero-padded unfold => OOB logit 0)
    float2 lg[9];
#pragma unroll
    for (int t = 0; t < 9; ++t) {
        const int dy = ((t / 3) - 1) * 2;
        const int dx = ((t % 3) - 1) * 2;
        const int ny = y + dy;
        const int nx = x0 + dx;           // even; pair valid iff 0<=nx<=54
        float2 s = make_float2(0.f, 0.f);
        if (active && (unsigned)ny < HH && (unsigned)nx < (WW - 1)) {
            const float* kb = k + base + (size_t)(ny * WW + nx);
#pragma unroll
            for (int d = 0; d < QCH; ++d) {
                const float2 kv = *reinterpret_cast<const float2*>(kb + (size_t)d * NN);
                s.x = fmaf(qv[d].x, kv.x, s.x);
                s.y = fmaf(qv[d].y, kv.y, s.y);
            }
        }
        lg[t] = s;
        part[qtr][t][xi] = s;
    }
    __syncthreads();

    // combine the 4 quarters' partials, scale
#pragma unroll
    for (int o = 1; o < NQ; ++o) {
        const int oq = (qtr + o) & 3;
#pragma unroll
        for (int t = 0; t < 9; ++t) {
            const float2 p = part[oq][t][xi];
            lg[t].x += p.x;
            lg[t].y += p.y;
        }
    }
#pragma unroll
    for (int t = 0; t < 9; ++t) { lg[t].x *= SCALE; lg[t].y *= SCALE; }

    // softmax over 9 taps, componentwise (each quarter duplicates; cheap)
    float mx = lg[0].x, my = lg[0].y;
#pragma unroll
    for (int t = 1; t < 9; ++t) { mx = fmaxf(mx, lg[t].x); my = fmaxf(my, lg[t].y); }
    float sx = 0.f, sy = 0.f;
#pragma unroll
    for (int t = 0; t < 9; ++t) {
        lg[t].x = __expf(lg[t].x - mx); sx += lg[t].x;
        lg[t].y = __expf(lg[t].y - my); sy += lg[t].y;
    }
    const float ix = 1.f / sx, iy = 1.f / sy;

    // PV accumulate over this quarter's 8 channels
    float2 acc[QCH];
#pragma unroll
    for (int d = 0; d < QCH; ++d) acc[d] = make_float2(0.f, 0.f);
#pragma unroll
    for (int t = 0; t < 9; ++t) {
        const int dy = ((t / 3) - 1) * 2;
        const int dx = ((t % 3) - 1) * 2;
        const int ny = y + dy;
        const int nx = x0 + dx;
        if (active && (unsigned)ny < HH && (unsigned)nx < (WW - 1)) {
            const float wx = lg[t].x * ix;
            const float wy = lg[t].y * iy;
            const float* vb = v + base + (size_t)(ny * WW + nx);
#pragma unroll
            for (int d = 0; d < QCH; ++d) {
                const float2 vv = *reinterpret_cast<const float2*>(vb + (size_t)d * NN);
                acc[d].x = fmaf(wx, vv.x, acc[d].x);
                acc[d].y = fmaf(wy, vv.y, acc[d].y);
            }
        }
    }

    // out[b, n, head*32 + qtr*8 + d]: 8 contiguous floats per pixel (2x float4)
    if (active) {
        float* ob0 = out + ((size_t)b * NN + n0) * CC + (size_t)head * HD + (size_t)qtr * QCH;
        float* ob1 = ob0 + CC;
        float4 s0 = make_float4(acc[0].x, acc[1].x, acc[2].x, acc[3].x);
        float4 s1 = make_float4(acc[4].x, acc[5].x, acc[6].x, acc[7].x);
        float4 s2 = make_float4(acc[0].y, acc[1].y, acc[2].y, acc[3].y);
        float4 s3 = make_float4(acc[4].y, acc[5].y, acc[6].y, acc[7].y);
        reinterpret_cast<float4*>(ob0)[0] = s0;
        reinterpret_cast<float4*>(ob0)[1] = s1;
        reinterpret_cast<float4*>(ob1)[0] = s2;
        reinterpret_cast<float4*>(ob1)[1] = s3;
    }
}

extern "C" void kernel_launch(void* const* d_in, const int* in_sizes, int n_in,
                              void* d_out, int out_size, void* d_ws, size_t ws_size,
                              hipStream_t stream) {
    const float* q = (const float*)d_in[0];
    const float* k = (const float*)d_in[1];
    const float* v = (const float*)d_in[2];
    float* out = (float*)d_out;

    dim3 block(PAIRS_PER_BLK, NQ);
    dim3 grid((NPAIRS + PAIRS_PER_BLK - 1) / PAIRS_PER_BLK, BB * NHEADS);
    dilate_attn_kernel<<<grid, block, 0, stream>>>(q, k, v, out);
}